// Round 3
// baseline (153.051 us; speedup 1.0000x reference)
//
#include <hip/hip_runtime.h>
#include <cstdint>
#include <cstddef>

#define BB 2
#define NN 6
#define CINC 256
#define HH 16
#define WW 44
#define DD 59
#define CO 64
#define PIXN 704       // H*W
#define OTOT 123       // D+COUT
#define XX 128
#define YY 128
#define ZZ 7
#define KC 128         // K-chunk staged in LDS

// ---------------- kernel 0: lapack_lite-style replica of inv(f32) (DO NOT
// TOUCH inv body — numerics verified R16 PASS) + fused W-transpose to
// wt[k][o] padded to 128 cols (zeros for o>=123).
__global__ __launch_bounds__(512) void k_inv(const float* __restrict__ c2e,
    float* __restrict__ e2c, const float* __restrict__ wd, float* __restrict__ wt) {
  int t = threadIdx.x;
  if (blockIdx.x == 0 && t < BB * NN) {
    const float* M = c2e + t * 16;
    float A[4][4];
    int ipiv[4];
    for (int i = 0; i < 4; ++i)
      for (int j = 0; j < 4; ++j) A[i][j] = M[i * 4 + j];
    // ---- sgetf2 ----
    for (int j = 0; j < 4; ++j) {
      int p = j;
      float mx = fabsf(A[j][j]);
      for (int i = j + 1; i < 4; ++i) {
        float v = fabsf(A[i][j]);
        if (v > mx) { mx = v; p = i; }
      }
      ipiv[j] = p;
      if (p != j)
        for (int k = 0; k < 4; ++k) { float tmp = A[j][k]; A[j][k] = A[p][k]; A[p][k] = tmp; }
      if (j < 3) {
        float r = __fdiv_rn(1.0f, A[j][j]);
        for (int i = j + 1; i < 4; ++i) A[i][j] = __fmul_rn(A[i][j], r);
        for (int i = j + 1; i < 4; ++i)
          for (int k = j + 1; k < 4; ++k)
            A[i][k] = __fsub_rn(A[i][k], __fmul_rn(A[i][j], A[j][k]));
      }
    }
    // ---- strti2 ----
    for (int j = 0; j < 4; ++j) {
      A[j][j] = __fdiv_rn(1.0f, A[j][j]);
      float ajj = -A[j][j];
      for (int j2 = 0; j2 < j; ++j2) {
        float temp = A[j2][j];
        if (temp != 0.0f) {
          for (int i = 0; i < j2; ++i)
            A[i][j] = __fadd_rn(A[i][j], __fmul_rn(temp, A[i][j2]));
          A[j2][j] = __fmul_rn(temp, A[j2][j2]);
        }
      }
      for (int i = 0; i < j; ++i)
        A[i][j] = __fmul_rn(ajj, A[i][j]);
    }
    // ---- sgetri sweep ----
    float work[4];
    for (int j = 3; j >= 0; --j) {
      for (int i = j + 1; i < 4; ++i) { work[i] = A[i][j]; A[i][j] = 0.0f; }
      for (int k = j + 1; k < 4; ++k) {
        float temp = -work[k];
        for (int i = 0; i < 4; ++i)
          A[i][j] = __fadd_rn(A[i][j], __fmul_rn(temp, A[i][k]));
      }
    }
    // ---- column interchanges ----
    for (int j = 2; j >= 0; --j) {
      int jp = ipiv[j];
      if (jp != j)
        for (int i = 0; i < 4; ++i) { float tmp = A[i][j]; A[i][j] = A[i][jp]; A[i][jp] = tmp; }
    }
    float* O = e2c + t * 12;
    for (int i = 0; i < 3; ++i)
      for (int j = 0; j < 4; ++j) O[i * 4 + j] = A[i][j];
  }
  // W transpose: wt[k*128 + o] = wd[o*256 + k]   (64 blocks x 512 = 32768)
  int idx = blockIdx.x * 512 + t;
  int k = idx >> 7, o = idx & 127;
  wt[idx] = (o < OTOT) ? wd[o * 256 + k] : 0.f;
}

// ---------------- kernel 1: GEMM x = F^T * W^T  (pure, no bias/softmax)
// grid 264 = 12 bn x 11 px-tiles(64) x 2 o-tiles(64). 256 thr / 4 waves,
// each wave owns a K-quarter; 8px x 8o register tile per lane.
__global__ __launch_bounds__(256) void k_gemm2(const float* __restrict__ img,
    const float* __restrict__ wt, float* __restrict__ xws) {
  __shared__ float smem[2 * KC * 68];   // 69,632 B: fbuf | wbuf (reused for reduce)
  float* fb = smem;
  float* wb = smem + KC * 68;
  const int tid = threadIdx.x;
  const int bid = blockIdx.x;
  const int ot  = bid & 1;
  const int pt  = (bid >> 1) % 11;
  const int bn  = bid / 22;
  const int px0 = pt * 64;
  const int o0  = ot * 64;
  const int lane = tid & 63;
  const int wv   = tid >> 6;
  const int pxg  = lane & 7;   // px-group: px = pxg*8 + i
  const int og   = lane >> 3;  // o-group:  o  = og*8  + j

  const float* fsrc = img + (size_t)bn * CINC * PIXN + px0;  // rows [k][704]
  const float* wsrc = wt + o0;                               // rows [k][128]

  float acc[8][8];
#pragma unroll
  for (int i = 0; i < 8; ++i)
#pragma unroll
    for (int j = 0; j < 8; ++j) acc[i][j] = 0.f;

  for (int chunk = 0; chunk < 2; ++chunk) {
    __syncthreads();
    // stage F chunk: 128k x 64px, aligned float4 copies, conflict-free
#pragma unroll
    for (int r = 0; r < 8; ++r) {
      int idx = r * 256 + tid;            // 0..2047
      int k = idx >> 4, pq = idx & 15;
      float4 v = *(const float4*)(fsrc + (size_t)(chunk * KC + k) * PIXN + pq * 4);
      *(float4*)(fb + k * 68 + pq * 4) = v;
    }
    // stage W chunk: 128k x 64o
#pragma unroll
    for (int r = 0; r < 8; ++r) {
      int idx = r * 256 + tid;
      int k = idx >> 4, oq = idx & 15;
      float4 v = *(const float4*)(wsrc + (size_t)(chunk * KC + k) * 128 + oq * 4);
      *(float4*)(wb + k * 68 + oq * 4) = v;
    }
    __syncthreads();
    // wave wv covers k in [wv*32, wv*32+32) of this chunk
    for (int ks = 0; ks < 8; ++ks) {
      int kk0 = wv * 32 + ks * 4;
      float fv[4][8], wvv[4][8];
#pragma unroll
      for (int kk = 0; kk < 4; ++kk) {
        const float* fr = fb + (kk0 + kk) * 68 + pxg * 8;
        const float* wr = wb + (kk0 + kk) * 68 + og * 8;
        float4 a = *(const float4*)(fr);
        float4 b = *(const float4*)(fr + 4);
        float4 c = *(const float4*)(wr);
        float4 d = *(const float4*)(wr + 4);
        fv[kk][0] = a.x; fv[kk][1] = a.y; fv[kk][2] = a.z; fv[kk][3] = a.w;
        fv[kk][4] = b.x; fv[kk][5] = b.y; fv[kk][6] = b.z; fv[kk][7] = b.w;
        wvv[kk][0] = c.x; wvv[kk][1] = c.y; wvv[kk][2] = c.z; wvv[kk][3] = c.w;
        wvv[kk][4] = d.x; wvv[kk][5] = d.y; wvv[kk][6] = d.z; wvv[kk][7] = d.w;
      }
#pragma unroll
      for (int kk = 0; kk < 4; ++kk)
#pragma unroll
        for (int i = 0; i < 8; ++i)
#pragma unroll
          for (int j = 0; j < 8; ++j)
            acc[i][j] += fv[kk][i] * wvv[kk][j];
    }
  }
  // ---- K-quarter reduce across the 4 waves (lane stride 68 -> uniform banks)
  __syncthreads();
  if (wv > 0) {
    float* dst = smem + (wv - 1) * 4352 + lane * 68;
#pragma unroll
    for (int i = 0; i < 8; ++i) {
      *(float4*)(dst + i * 8)     = make_float4(acc[i][0], acc[i][1], acc[i][2], acc[i][3]);
      *(float4*)(dst + i * 8 + 4) = make_float4(acc[i][4], acc[i][5], acc[i][6], acc[i][7]);
    }
  }
  __syncthreads();
  if (wv == 0) {
#pragma unroll
    for (int r = 0; r < 3; ++r) {
      const float* srcp = smem + r * 4352 + lane * 68;
#pragma unroll
      for (int i = 0; i < 8; ++i) {
        float4 v0 = *(const float4*)(srcp + i * 8);
        float4 v1 = *(const float4*)(srcp + i * 8 + 4);
        acc[i][0] += v0.x; acc[i][1] += v0.y; acc[i][2] += v0.z; acc[i][3] += v0.w;
        acc[i][4] += v1.x; acc[i][5] += v1.y; acc[i][6] += v1.z; acc[i][7] += v1.w;
      }
    }
    float* xrow = xws + ((size_t)bn * PIXN + px0) * 128 + o0 + og * 8;
#pragma unroll
    for (int i = 0; i < 8; ++i) {
      int px = pxg * 8 + i;
      *(float4*)(xrow + px * 128)     = make_float4(acc[i][0], acc[i][1], acc[i][2], acc[i][3]);
      *(float4*)(xrow + px * 128 + 4) = make_float4(acc[i][4], acc[i][5], acc[i][6], acc[i][7]);
    }
  }
}

// ---------------- kernel 1b: bias + softmax + depth/feat writeback
// (inner logic verbatim from the verified fused epilogue; source is xws)
__global__ __launch_bounds__(512) void k_soft(const float* __restrict__ xws,
    const float* __restrict__ bd, float* __restrict__ depth_out,
    float* __restrict__ feat_ws) {
  __shared__ float sb[64 * 129];
  __shared__ float pm[8 * 64];
  __shared__ float psum[8 * 64];
  __shared__ float m_l[64], rs_l[64];
  const int tid  = threadIdx.x;
  const int bn   = blockIdx.x / 11;
  const int tile = blockIdx.x % 11;
  const int px0  = tile * 64;
  const float* xrow = xws + ((size_t)bn * PIXN + px0) * 128;
  for (int idx = tid; idx < 64 * 128; idx += 512) {
    int p = idx >> 7, o = idx & 127;
    float v = xrow[idx];
    v += (o < OTOT) ? bd[o] : 0.f;
    sb[p * 129 + o] = v;
  }
  __syncthreads();
  const int px  = tid & 63;
  const int rep = tid >> 6;
  const int d0 = rep * 8;
  const int d1 = (d0 + 8 < DD) ? d0 + 8 : DD;
  float mm = -3.4e38f;
  for (int d = d0; d < d1; ++d) mm = fmaxf(mm, sb[px * 129 + d]);
  pm[rep * 64 + px] = mm;
  __syncthreads();
  float m = pm[px];
#pragma unroll
  for (int r2 = 1; r2 < 8; ++r2) m = fmaxf(m, pm[r2 * 64 + px]);
  float ss = 0.f;
  for (int d = d0; d < d1; ++d) ss += expf(sb[px * 129 + d] - m);
  psum[rep * 64 + px] = ss;
  __syncthreads();
  float s = psum[px];
#pragma unroll
  for (int r2 = 1; r2 < 8; ++r2) s += psum[r2 * 64 + px];
  if (rep == 0) { m_l[px] = m; rs_l[px] = 1.f / s; }
  __syncthreads();
  float* drow = depth_out + ((size_t)bn * PIXN + px0) * DD;
  for (int idx = tid; idx < 64 * DD; idx += 512) {
    int p2 = idx / DD;
    int d  = idx - p2 * DD;
    drow[idx] = expf(sb[p2 * 129 + d] - m_l[p2]) * rs_l[p2];
  }
  float* frow = feat_ws + ((size_t)bn * PIXN + px0) * CO;
  for (int idx = tid; idx < 64 * CO; idx += 512) {
    int p2 = idx >> 6, of = idx & 63;
    frow[idx] = sb[p2 * 129 + 59 + of];
  }
}

// ---------------- kernel 2: per-(b,x,y,n,z) projection -> weight + pixel index
// DO NOT TOUCH — numerics verified (R16 PASS).
__global__ __launch_bounds__(256) void k_proj(const float* __restrict__ e2c,
    const float* __restrict__ Kin, const float* __restrict__ depth_out,
    float* __restrict__ w_ws, unsigned short* __restrict__ pix_ws) {
  int t = blockIdx.x * 256 + threadIdx.x;
  const int TOT = BB * YY * XX * 48;
  if (t >= TOT) return;
  int cell = t / 48;
  int nz = t - cell * 48;
  int b = cell >> 14;
  int rem = cell & 16383;
  int y = rem >> 7;
  int x = rem & 127;
  int n = nz >> 3;
  int z = nz & 7;
  float w = 0.f;
  int pix = 0;
  if (z < ZZ) {
    int bn = b * NN + n;
    const float* M = e2c + bn * 12;
    float vx = __fadd_rn(__fmul_rn((float)x, 0.8f), -51.2f);
    float vy = __fadd_rn(__fmul_rn((float)y, 0.8f), -51.2f);
    float vz = __fadd_rn(__fmul_rn((float)z, 1.0f), -2.5f);
    float c0 = __fadd_rn(__fadd_rn(__fadd_rn(__fmul_rn(M[0], vx), __fmul_rn(M[1], vy)),
                                   __fmul_rn(M[2], vz)), M[3]);
    float c1 = __fadd_rn(__fadd_rn(__fadd_rn(__fmul_rn(M[4], vx), __fmul_rn(M[5], vy)),
                                   __fmul_rn(M[6], vz)), M[7]);
    float zc = __fadd_rn(__fadd_rn(__fadd_rn(__fmul_rn(M[8], vx), __fmul_rn(M[9], vy)),
                                   __fmul_rn(M[10], vz)), M[11]);
    bool val = (zc > 0.5f);
    float zs = fmaxf(zc, 0.1f);
    float u = __fdiv_rn(c0, zs);
    float v = __fdiv_rn(c1, zs);
    const float* Kp = Kin + bn * 9;
    float imx = __fadd_rn(__fmul_rn(Kp[0], u), Kp[2]);
    float imy = __fadd_rn(__fmul_rn(Kp[4], v), Kp[5]);
    float fcx = __fmul_rn(imx, 0.0625f);
    float fcy = __fmul_rn(imy, 0.0625f);
    val = val && (fcx >= 0.f) && (fcx < 44.f) && (fcy >= 0.f) && (fcy < 16.f);
    int dbin = (int)truncf(__fsub_rn(zc, 1.0f));
    val = val && (dbin >= 0) && (dbin < DD);
    int ui = (int)truncf(fminf(fmaxf(fcx, 0.f), 43.f));
    int vi = (int)truncf(fminf(fmaxf(fcy, 0.f), 15.f));
    int d = min(max(dbin, 0), DD - 1);
    pix = vi * WW + ui;
    if (val) w = depth_out[((size_t)bn * PIXN + pix) * DD + d];
  }
  w_ws[t] = w;
  pix_ws[t] = (unsigned short)pix;
}

// ---------------- kernel 3: gather-accumulate into BEV
// v3: multi-tile blocks. R2 post-mortem: Occupancy 25% + all pipes <10% =
// wave-slot starvation from 2048 one-shot 1024-thread blocks, NOT gather
// latency (which is why R1's 8-way batching was neutral). Now grid=512,
// each block walks 4 tiles (striped gb = bid + ti*512 for load balance) and
// prefetches the next tile's w/pix before walking the current one. Inner
// ballot walk + fmaf order + epilogue are VERBATIM (numerics identical);
// only an extra __syncthreads covers the sm[] WAR hazard between tiles.
__global__ __launch_bounds__(1024) void k_scatter(const float* __restrict__ w_ws,
    const unsigned short* __restrict__ pix_ws, const float* __restrict__ feat_ws,
    float* __restrict__ bev) {
  __shared__ float sm[64 * 17];
  int tid = threadIdx.x;
  int lane = tid & 63;
  int wv = tid >> 6;
  // prefetch tile 0
  float wval = 0.f;
  int pixv = 0;
  {
    int gb = blockIdx.x;
    int b = gb >> 10, rem = gb & 1023, y = rem >> 3, x0 = (rem & 7) << 4;
    int base = ((b * YY + y) * XX + x0 + wv) * 48;
    if (lane < 48) {
      wval = w_ws[base + lane];
      pixv = pix_ws[base + lane];
    }
  }
  for (int ti = 0; ti < 4; ++ti) {
    int gb = blockIdx.x + ti * 512;
    int b = gb >> 10, rem = gb & 1023, y = rem >> 3, x0 = (rem & 7) << 4;
    // prefetch next tile's w/pix (hides its HBM read under this tile's walk)
    float wn = 0.f;
    int pn = 0;
    if (ti < 3) {
      int gn = blockIdx.x + (ti + 1) * 512;
      int b2 = gn >> 10, rem2 = gn & 1023, y2 = rem2 >> 3, x02 = (rem2 & 7) << 4;
      int base2 = ((b2 * YY + y2) * XX + x02 + wv) * 48;
      if (lane < 48) {
        wn = w_ws[base2 + lane];
        pn = pix_ws[base2 + lane];
      }
    }
    int iwval = __float_as_int(wval);
    unsigned long long mask = __ballot(wval != 0.f);
    float acc = 0.f;
    const float* fbase = feat_ws + ((size_t)b * NN * PIXN << 6);
    while (mask) {
#define POPBIT(sv) int sv = -1; if (mask) { sv = (int)__builtin_ctzll(mask); mask &= mask - 1; }
      POPBIT(s0) POPBIT(s1) POPBIT(s2) POPBIT(s3)
      POPBIT(s4) POPBIT(s5) POPBIT(s6) POPBIT(s7)
#undef POPBIT
#define ENTRY(sv, wbv, frv) \
      float wbv = 0.f; const float* frv; \
      { int sl = (sv < 0) ? 0 : sv; \
        int pbl = __builtin_amdgcn_readlane(pixv, sl); \
        if (sv >= 0) wbv = __int_as_float(__builtin_amdgcn_readlane(iwval, sl)); \
        frv = fbase + ((((size_t)(sl >> 3) * PIXN) + pbl) << 6); }
      ENTRY(s0, wb0, fr0) ENTRY(s1, wb1, fr1) ENTRY(s2, wb2, fr2) ENTRY(s3, wb3, fr3)
      ENTRY(s4, wb4, fr4) ENTRY(s5, wb5, fr5) ENTRY(s6, wb6, fr6) ENTRY(s7, wb7, fr7)
#undef ENTRY
      float v0 = fr0[lane], v1 = fr1[lane], v2 = fr2[lane], v3 = fr3[lane];
      float v4 = fr4[lane], v5 = fr5[lane], v6 = fr6[lane], v7 = fr7[lane];
      acc = fmaf(wb0, v0, acc);
      acc = fmaf(wb1, v1, acc);
      acc = fmaf(wb2, v2, acc);
      acc = fmaf(wb3, v3, acc);
      acc = fmaf(wb4, v4, acc);
      acc = fmaf(wb5, v5, acc);
      acc = fmaf(wb6, v6, acc);
      acc = fmaf(wb7, v7, acc);
    }
    sm[lane * 17 + wv] = acc;
    __syncthreads();
    int o = tid >> 4, xi = tid & 15;
    bev[(((size_t)b * CO + o) * YY + y) * XX + x0 + xi] = sm[o * 17 + xi];
    __syncthreads();   // sm WAR hazard before next tile overwrites it
    wval = wn;
    pixv = pn;
  }
}

extern "C" void kernel_launch(void* const* d_in, const int* in_sizes, int n_in,
                              void* d_out, int out_size, void* d_ws, size_t ws_size,
                              hipStream_t stream) {
  const float* img = (const float*)d_in[0];
  const float* c2e = (const float*)d_in[1];
  const float* Kin = (const float*)d_in[2];
  const float* wd  = (const float*)d_in[3];
  const float* bd  = (const float*)d_in[4];

  float* bev = (float*)d_out;
  float* depth_out = bev + (size_t)BB * CO * YY * XX;

  float* e2c = (float*)d_ws;
  float* feat_ws = (float*)((char*)d_ws + 2048);
  float* w_ws = feat_ws + (size_t)BB * NN * PIXN * CO;
  unsigned short* pix_ws = (unsigned short*)(w_ws + (size_t)BB * YY * XX * 48);
  // Aliases (disjoint lifetimes in stream order):
  //   xws (4.33 MB, k_gemm2->k_soft) sits on w_ws (6.29 MB, k_proj->k_scatter)
  //   wt  (128 KB,  k_inv->k_gemm2)  sits on pix_ws (3.1 MB, k_proj->k_scatter)
  float* xws = w_ws;
  float* wt  = (float*)pix_ws;

  hipLaunchKernelGGL(k_inv, dim3(64), dim3(512), 0, stream, c2e, e2c, wd, wt);
  hipLaunchKernelGGL(k_gemm2, dim3(BB * NN * 22), dim3(256), 0, stream, img, wt, xws);
  hipLaunchKernelGGL(k_soft, dim3(BB * NN * 11), dim3(512), 0, stream, xws, bd, depth_out, feat_ws);
  hipLaunchKernelGGL(k_proj, dim3((BB * YY * XX * 48) / 256), dim3(256), 0, stream,
                     e2c, Kin, depth_out, w_ws, pix_ws);
  hipLaunchKernelGGL(k_scatter, dim3(512), dim3(1024), 0, stream,
                     w_ws, pix_ws, feat_ws, bev);
}

// Round 4
// 121.118 us; speedup vs baseline: 1.2637x; 1.2637x over previous
//
#include <hip/hip_runtime.h>
#include <cstdint>
#include <cstddef>

#define BB 2
#define NN 6
#define CINC 256
#define HH 16
#define WW 44
#define DD 59
#define CO 64
#define PIXN 704       // H*W
#define OTOT 123       // D+COUT
#define XX 128
#define YY 128
#define ZZ 7
#define KC 128         // K-chunk staged in LDS

// ---------------- kernel 0: lapack_lite-style replica of inv(f32) (DO NOT
// TOUCH inv body — numerics verified R16 PASS) + fused W-transpose to
// wt[k][o] padded to 128 cols (zeros for o>=123).
__global__ __launch_bounds__(512) void k_inv(const float* __restrict__ c2e,
    float* __restrict__ e2c, const float* __restrict__ wd, float* __restrict__ wt) {
  int t = threadIdx.x;
  if (blockIdx.x == 0 && t < BB * NN) {
    const float* M = c2e + t * 16;
    float A[4][4];
    int ipiv[4];
    for (int i = 0; i < 4; ++i)
      for (int j = 0; j < 4; ++j) A[i][j] = M[i * 4 + j];
    // ---- sgetf2 ----
    for (int j = 0; j < 4; ++j) {
      int p = j;
      float mx = fabsf(A[j][j]);
      for (int i = j + 1; i < 4; ++i) {
        float v = fabsf(A[i][j]);
        if (v > mx) { mx = v; p = i; }
      }
      ipiv[j] = p;
      if (p != j)
        for (int k = 0; k < 4; ++k) { float tmp = A[j][k]; A[j][k] = A[p][k]; A[p][k] = tmp; }
      if (j < 3) {
        float r = __fdiv_rn(1.0f, A[j][j]);
        for (int i = j + 1; i < 4; ++i) A[i][j] = __fmul_rn(A[i][j], r);
        for (int i = j + 1; i < 4; ++i)
          for (int k = j + 1; k < 4; ++k)
            A[i][k] = __fsub_rn(A[i][k], __fmul_rn(A[i][j], A[j][k]));
      }
    }
    // ---- strti2 ----
    for (int j = 0; j < 4; ++j) {
      A[j][j] = __fdiv_rn(1.0f, A[j][j]);
      float ajj = -A[j][j];
      for (int j2 = 0; j2 < j; ++j2) {
        float temp = A[j2][j];
        if (temp != 0.0f) {
          for (int i = 0; i < j2; ++i)
            A[i][j] = __fadd_rn(A[i][j], __fmul_rn(temp, A[i][j2]));
          A[j2][j] = __fmul_rn(temp, A[j2][j2]);
        }
      }
      for (int i = 0; i < j; ++i)
        A[i][j] = __fmul_rn(ajj, A[i][j]);
    }
    // ---- sgetri sweep ----
    float work[4];
    for (int j = 3; j >= 0; --j) {
      for (int i = j + 1; i < 4; ++i) { work[i] = A[i][j]; A[i][j] = 0.0f; }
      for (int k = j + 1; k < 4; ++k) {
        float temp = -work[k];
        for (int i = 0; i < 4; ++i)
          A[i][j] = __fadd_rn(A[i][j], __fmul_rn(temp, A[i][k]));
      }
    }
    // ---- column interchanges ----
    for (int j = 2; j >= 0; --j) {
      int jp = ipiv[j];
      if (jp != j)
        for (int i = 0; i < 4; ++i) { float tmp = A[i][j]; A[i][j] = A[i][jp]; A[i][jp] = tmp; }
    }
    float* O = e2c + t * 12;
    for (int i = 0; i < 3; ++i)
      for (int j = 0; j < 4; ++j) O[i * 4 + j] = A[i][j];
  }
  // W transpose: wt[k*128 + o] = wd[o*256 + k]   (64 blocks x 512 = 32768)
  int idx = blockIdx.x * 512 + t;
  int k = idx >> 7, o = idx & 127;
  wt[idx] = (o < OTOT) ? wd[o * 256 + k] : 0.f;
}

// ---------------- kernel 1: GEMM x = F^T * W^T  (pure, no bias/softmax)
// grid 264 = 12 bn x 11 px-tiles(64) x 2 o-tiles(64). 256 thr / 4 waves,
// each wave owns a K-quarter; 8px x 8o register tile per lane.
__global__ __launch_bounds__(256) void k_gemm2(const float* __restrict__ img,
    const float* __restrict__ wt, float* __restrict__ xws) {
  __shared__ float smem[2 * KC * 68];   // 69,632 B: fbuf | wbuf (reused for reduce)
  float* fb = smem;
  float* wb = smem + KC * 68;
  const int tid = threadIdx.x;
  const int bid = blockIdx.x;
  const int ot  = bid & 1;
  const int pt  = (bid >> 1) % 11;
  const int bn  = bid / 22;
  const int px0 = pt * 64;
  const int o0  = ot * 64;
  const int lane = tid & 63;
  const int wv   = tid >> 6;
  const int pxg  = lane & 7;   // px-group: px = pxg*8 + i
  const int og   = lane >> 3;  // o-group:  o  = og*8  + j

  const float* fsrc = img + (size_t)bn * CINC * PIXN + px0;  // rows [k][704]
  const float* wsrc = wt + o0;                               // rows [k][128]

  float acc[8][8];
#pragma unroll
  for (int i = 0; i < 8; ++i)
#pragma unroll
    for (int j = 0; j < 8; ++j) acc[i][j] = 0.f;

  for (int chunk = 0; chunk < 2; ++chunk) {
    __syncthreads();
    // stage F chunk: 128k x 64px, aligned float4 copies, conflict-free
#pragma unroll
    for (int r = 0; r < 8; ++r) {
      int idx = r * 256 + tid;            // 0..2047
      int k = idx >> 4, pq = idx & 15;
      float4 v = *(const float4*)(fsrc + (size_t)(chunk * KC + k) * PIXN + pq * 4);
      *(float4*)(fb + k * 68 + pq * 4) = v;
    }
    // stage W chunk: 128k x 64o
#pragma unroll
    for (int r = 0; r < 8; ++r) {
      int idx = r * 256 + tid;
      int k = idx >> 4, oq = idx & 15;
      float4 v = *(const float4*)(wsrc + (size_t)(chunk * KC + k) * 128 + oq * 4);
      *(float4*)(wb + k * 68 + oq * 4) = v;
    }
    __syncthreads();
    // wave wv covers k in [wv*32, wv*32+32) of this chunk
    for (int ks = 0; ks < 8; ++ks) {
      int kk0 = wv * 32 + ks * 4;
      float fv[4][8], wvv[4][8];
#pragma unroll
      for (int kk = 0; kk < 4; ++kk) {
        const float* fr = fb + (kk0 + kk) * 68 + pxg * 8;
        const float* wr = wb + (kk0 + kk) * 68 + og * 8;
        float4 a = *(const float4*)(fr);
        float4 b = *(const float4*)(fr + 4);
        float4 c = *(const float4*)(wr);
        float4 d = *(const float4*)(wr + 4);
        fv[kk][0] = a.x; fv[kk][1] = a.y; fv[kk][2] = a.z; fv[kk][3] = a.w;
        fv[kk][4] = b.x; fv[kk][5] = b.y; fv[kk][6] = b.z; fv[kk][7] = b.w;
        wvv[kk][0] = c.x; wvv[kk][1] = c.y; wvv[kk][2] = c.z; wvv[kk][3] = c.w;
        wvv[kk][4] = d.x; wvv[kk][5] = d.y; wvv[kk][6] = d.z; wvv[kk][7] = d.w;
      }
#pragma unroll
      for (int kk = 0; kk < 4; ++kk)
#pragma unroll
        for (int i = 0; i < 8; ++i)
#pragma unroll
          for (int j = 0; j < 8; ++j)
            acc[i][j] += fv[kk][i] * wvv[kk][j];
    }
  }
  // ---- K-quarter reduce across the 4 waves (lane stride 68 -> uniform banks)
  __syncthreads();
  if (wv > 0) {
    float* dst = smem + (wv - 1) * 4352 + lane * 68;
#pragma unroll
    for (int i = 0; i < 8; ++i) {
      *(float4*)(dst + i * 8)     = make_float4(acc[i][0], acc[i][1], acc[i][2], acc[i][3]);
      *(float4*)(dst + i * 8 + 4) = make_float4(acc[i][4], acc[i][5], acc[i][6], acc[i][7]);
    }
  }
  __syncthreads();
  if (wv == 0) {
#pragma unroll
    for (int r = 0; r < 3; ++r) {
      const float* srcp = smem + r * 4352 + lane * 68;
#pragma unroll
      for (int i = 0; i < 8; ++i) {
        float4 v0 = *(const float4*)(srcp + i * 8);
        float4 v1 = *(const float4*)(srcp + i * 8 + 4);
        acc[i][0] += v0.x; acc[i][1] += v0.y; acc[i][2] += v0.z; acc[i][3] += v0.w;
        acc[i][4] += v1.x; acc[i][5] += v1.y; acc[i][6] += v1.z; acc[i][7] += v1.w;
      }
    }
    float* xrow = xws + ((size_t)bn * PIXN + px0) * 128 + o0 + og * 8;
#pragma unroll
    for (int i = 0; i < 8; ++i) {
      int px = pxg * 8 + i;
      *(float4*)(xrow + px * 128)     = make_float4(acc[i][0], acc[i][1], acc[i][2], acc[i][3]);
      *(float4*)(xrow + px * 128 + 4) = make_float4(acc[i][4], acc[i][5], acc[i][6], acc[i][7]);
    }
  }
}

// ---------------- kernel 1b: bias + softmax + depth/feat writeback
// (inner logic verbatim from the verified fused epilogue; source is xws)
__global__ __launch_bounds__(512) void k_soft(const float* __restrict__ xws,
    const float* __restrict__ bd, float* __restrict__ depth_out,
    float* __restrict__ feat_ws) {
  __shared__ float sb[64 * 129];
  __shared__ float pm[8 * 64];
  __shared__ float psum[8 * 64];
  __shared__ float m_l[64], rs_l[64];
  const int tid  = threadIdx.x;
  const int bn   = blockIdx.x / 11;
  const int tile = blockIdx.x % 11;
  const int px0  = tile * 64;
  const float* xrow = xws + ((size_t)bn * PIXN + px0) * 128;
  for (int idx = tid; idx < 64 * 128; idx += 512) {
    int p = idx >> 7, o = idx & 127;
    float v = xrow[idx];
    v += (o < OTOT) ? bd[o] : 0.f;
    sb[p * 129 + o] = v;
  }
  __syncthreads();
  const int px  = tid & 63;
  const int rep = tid >> 6;
  const int d0 = rep * 8;
  const int d1 = (d0 + 8 < DD) ? d0 + 8 : DD;
  float mm = -3.4e38f;
  for (int d = d0; d < d1; ++d) mm = fmaxf(mm, sb[px * 129 + d]);
  pm[rep * 64 + px] = mm;
  __syncthreads();
  float m = pm[px];
#pragma unroll
  for (int r2 = 1; r2 < 8; ++r2) m = fmaxf(m, pm[r2 * 64 + px]);
  float ss = 0.f;
  for (int d = d0; d < d1; ++d) ss += expf(sb[px * 129 + d] - m);
  psum[rep * 64 + px] = ss;
  __syncthreads();
  float s = psum[px];
#pragma unroll
  for (int r2 = 1; r2 < 8; ++r2) s += psum[r2 * 64 + px];
  if (rep == 0) { m_l[px] = m; rs_l[px] = 1.f / s; }
  __syncthreads();
  float* drow = depth_out + ((size_t)bn * PIXN + px0) * DD;
  for (int idx = tid; idx < 64 * DD; idx += 512) {
    int p2 = idx / DD;
    int d  = idx - p2 * DD;
    drow[idx] = expf(sb[p2 * 129 + d] - m_l[p2]) * rs_l[p2];
  }
  float* frow = feat_ws + ((size_t)bn * PIXN + px0) * CO;
  for (int idx = tid; idx < 64 * CO; idx += 512) {
    int p2 = idx >> 6, of = idx & 63;
    frow[idx] = sb[p2 * 129 + 59 + of];
  }
}

// ---------------- kernel 2: per-(b,x,y,n,z) projection -> weight + pixel index
// DO NOT TOUCH — numerics verified (R16 PASS).
__global__ __launch_bounds__(256) void k_proj(const float* __restrict__ e2c,
    const float* __restrict__ Kin, const float* __restrict__ depth_out,
    float* __restrict__ w_ws, unsigned short* __restrict__ pix_ws) {
  int t = blockIdx.x * 256 + threadIdx.x;
  const int TOT = BB * YY * XX * 48;
  if (t >= TOT) return;
  int cell = t / 48;
  int nz = t - cell * 48;
  int b = cell >> 14;
  int rem = cell & 16383;
  int y = rem >> 7;
  int x = rem & 127;
  int n = nz >> 3;
  int z = nz & 7;
  float w = 0.f;
  int pix = 0;
  if (z < ZZ) {
    int bn = b * NN + n;
    const float* M = e2c + bn * 12;
    float vx = __fadd_rn(__fmul_rn((float)x, 0.8f), -51.2f);
    float vy = __fadd_rn(__fmul_rn((float)y, 0.8f), -51.2f);
    float vz = __fadd_rn(__fmul_rn((float)z, 1.0f), -2.5f);
    float c0 = __fadd_rn(__fadd_rn(__fadd_rn(__fmul_rn(M[0], vx), __fmul_rn(M[1], vy)),
                                   __fmul_rn(M[2], vz)), M[3]);
    float c1 = __fadd_rn(__fadd_rn(__fadd_rn(__fmul_rn(M[4], vx), __fmul_rn(M[5], vy)),
                                   __fmul_rn(M[6], vz)), M[7]);
    float zc = __fadd_rn(__fadd_rn(__fadd_rn(__fmul_rn(M[8], vx), __fmul_rn(M[9], vy)),
                                   __fmul_rn(M[10], vz)), M[11]);
    bool val = (zc > 0.5f);
    float zs = fmaxf(zc, 0.1f);
    float u = __fdiv_rn(c0, zs);
    float v = __fdiv_rn(c1, zs);
    const float* Kp = Kin + bn * 9;
    float imx = __fadd_rn(__fmul_rn(Kp[0], u), Kp[2]);
    float imy = __fadd_rn(__fmul_rn(Kp[4], v), Kp[5]);
    float fcx = __fmul_rn(imx, 0.0625f);
    float fcy = __fmul_rn(imy, 0.0625f);
    val = val && (fcx >= 0.f) && (fcx < 44.f) && (fcy >= 0.f) && (fcy < 16.f);
    int dbin = (int)truncf(__fsub_rn(zc, 1.0f));
    val = val && (dbin >= 0) && (dbin < DD);
    int ui = (int)truncf(fminf(fmaxf(fcx, 0.f), 43.f));
    int vi = (int)truncf(fminf(fmaxf(fcy, 0.f), 15.f));
    int d = min(max(dbin, 0), DD - 1);
    pix = vi * WW + ui;
    if (val) w = depth_out[((size_t)bn * PIXN + pix) * DD + d];
  }
  w_ws[t] = w;
  pix_ws[t] = (unsigned short)pix;
}

// ---------------- kernel 3: gather-accumulate into BEV
// v4: entry x column parallel (no ballot walk). R3 post-mortem: one heavy
// 16-cell tile cost ~12 us under the wave-per-cell serial walk — unmodelable
// ~4000cy per 8-entry batch + 16-wave barrier imbalance. Now: 256-thr/4-wave
// blocks; a wave covers 4 cells at once with lane=(cell c=lane>>4, colquad
// q=lane&15); each lane owns float4 of output cols and iterates e=0..47
// ASCENDING: acc=fmaf(w[c][e], feat[e][q*4..], acc). Nonzero terms hit in the
// same ascending order as the verified walk; interleaved invalid terms are
// fmaf(0,finite,acc)==acc exactly (w>0 iff valid; pix always in-bounds) ->
// bev bit-identical. All 48 loads per cell are independent -> pipelined, one
// drain. w/pix staged to LDS coalesced (768 contiguous per block). Uniform
// __ballot skip for whole-wave-invalid e.
__global__ __launch_bounds__(256, 4) void k_scatter(const float* __restrict__ w_ws,
    const unsigned short* __restrict__ pix_ws, const float* __restrict__ feat_ws,
    float* __restrict__ bev) {
  __shared__ float sm_w[16 * 48];
  __shared__ int   sm_p[16 * 48];
  __shared__ float sm_o[16 * 67];
  const int tid = threadIdx.x;
  const int gb = blockIdx.x;
  const int b = gb >> 10;
  const int rem = gb & 1023;
  const int y = rem >> 3;
  const int x0 = (rem & 7) << 4;
  const int base768 = ((b * YY + y) * XX + x0) * 48;   // 16 cells contiguous
  for (int i = tid; i < 768; i += 256) {
    sm_w[i] = w_ws[base768 + i];
    sm_p[i] = (int)pix_ws[base768 + i];
  }
  __syncthreads();
  const int lane = tid & 63;
  const int wv = tid >> 6;
  const int c = lane >> 4;          // cell within wave (0..3)
  const int q = lane & 15;          // column quad (0..15)
  const int xi = wv * 4 + c;        // cell within block (0..15)
  const int wbase = xi * 48;
  const float* fbase = feat_ws + ((size_t)b * NN * PIXN << 6) + q * 4;
  float4 acc = make_float4(0.f, 0.f, 0.f, 0.f);
#pragma unroll
  for (int e = 0; e < 48; ++e) {
    float we = sm_w[wbase + e];
    if (__ballot(we != 0.f)) {
      int pe = sm_p[wbase + e];
      const float* fr = fbase + (((e >> 3) * PIXN + pe) << 6);
      float4 v = *(const float4*)fr;
      acc.x = fmaf(we, v.x, acc.x);
      acc.y = fmaf(we, v.y, acc.y);
      acc.z = fmaf(we, v.z, acc.z);
      acc.w = fmaf(we, v.w, acc.w);
    }
  }
  *(float4*)&sm_o[xi * 67 + q * 4] = acc;
  __syncthreads();
  // transposed bev write: 16-float contiguous x-runs per (b,o,y)
#pragma unroll
  for (int k = 0; k < 4; ++k) {
    int idx = k * 256 + tid;
    int o = idx >> 4, x2 = idx & 15;
    bev[(((size_t)b * CO + o) * YY + y) * XX + x0 + x2] = sm_o[x2 * 67 + o];
  }
}

extern "C" void kernel_launch(void* const* d_in, const int* in_sizes, int n_in,
                              void* d_out, int out_size, void* d_ws, size_t ws_size,
                              hipStream_t stream) {
  const float* img = (const float*)d_in[0];
  const float* c2e = (const float*)d_in[1];
  const float* Kin = (const float*)d_in[2];
  const float* wd  = (const float*)d_in[3];
  const float* bd  = (const float*)d_in[4];

  float* bev = (float*)d_out;
  float* depth_out = bev + (size_t)BB * CO * YY * XX;

  float* e2c = (float*)d_ws;
  float* feat_ws = (float*)((char*)d_ws + 2048);
  float* w_ws = feat_ws + (size_t)BB * NN * PIXN * CO;
  unsigned short* pix_ws = (unsigned short*)(w_ws + (size_t)BB * YY * XX * 48);
  // Aliases (disjoint lifetimes in stream order):
  //   xws (4.33 MB, k_gemm2->k_soft) sits on w_ws (6.29 MB, k_proj->k_scatter)
  //   wt  (128 KB,  k_inv->k_gemm2)  sits on pix_ws (3.1 MB, k_proj->k_scatter)
  float* xws = w_ws;
  float* wt  = (float*)pix_ws;

  hipLaunchKernelGGL(k_inv, dim3(64), dim3(512), 0, stream, c2e, e2c, wd, wt);
  hipLaunchKernelGGL(k_gemm2, dim3(BB * NN * 22), dim3(256), 0, stream, img, wt, xws);
  hipLaunchKernelGGL(k_soft, dim3(BB * NN * 11), dim3(512), 0, stream, xws, bd, depth_out, feat_ws);
  hipLaunchKernelGGL(k_proj, dim3((BB * YY * XX * 48) / 256), dim3(256), 0, stream,
                     e2c, Kin, depth_out, w_ws, pix_ws);
  hipLaunchKernelGGL(k_scatter, dim3(BB * YY * 8), dim3(256), 0, stream,
                     w_ws, pix_ws, feat_ws, bev);
}

// Round 8
// 120.188 us; speedup vs baseline: 1.2734x; 1.0077x over previous
//
#include <hip/hip_runtime.h>
#include <cstdint>
#include <cstddef>

#define BB 2
#define NN 6
#define CINC 256
#define HH 16
#define WW 44
#define DD 59
#define CO 64
#define PIXN 704       // H*W
#define OTOT 123       // D+COUT
#define XX 128
#define YY 128
#define ZZ 7
#define KC 128         // K-chunk staged in LDS

// ---------------- kernel 0: lapack_lite-style replica of inv(f32) (DO NOT
// TOUCH inv body — numerics verified R16 PASS) + fused W-transpose to
// wt[k][o] padded to 128 cols (zeros for o>=123).
__global__ __launch_bounds__(512) void k_inv(const float* __restrict__ c2e,
    float* __restrict__ e2c, const float* __restrict__ wd, float* __restrict__ wt) {
  int t = threadIdx.x;
  if (blockIdx.x == 0 && t < BB * NN) {
    const float* M = c2e + t * 16;
    float A[4][4];
    int ipiv[4];
    for (int i = 0; i < 4; ++i)
      for (int j = 0; j < 4; ++j) A[i][j] = M[i * 4 + j];
    // ---- sgetf2 ----
    for (int j = 0; j < 4; ++j) {
      int p = j;
      float mx = fabsf(A[j][j]);
      for (int i = j + 1; i < 4; ++i) {
        float v = fabsf(A[i][j]);
        if (v > mx) { mx = v; p = i; }
      }
      ipiv[j] = p;
      if (p != j)
        for (int k = 0; k < 4; ++k) { float tmp = A[j][k]; A[j][k] = A[p][k]; A[p][k] = tmp; }
      if (j < 3) {
        float r = __fdiv_rn(1.0f, A[j][j]);
        for (int i = j + 1; i < 4; ++i) A[i][j] = __fmul_rn(A[i][j], r);
        for (int i = j + 1; i < 4; ++i)
          for (int k = j + 1; k < 4; ++k)
            A[i][k] = __fsub_rn(A[i][k], __fmul_rn(A[i][j], A[j][k]));
      }
    }
    // ---- strti2 ----
    for (int j = 0; j < 4; ++j) {
      A[j][j] = __fdiv_rn(1.0f, A[j][j]);
      float ajj = -A[j][j];
      for (int j2 = 0; j2 < j; ++j2) {
        float temp = A[j2][j];
        if (temp != 0.0f) {
          for (int i = 0; i < j2; ++i)
            A[i][j] = __fadd_rn(A[i][j], __fmul_rn(temp, A[i][j2]));
          A[j2][j] = __fmul_rn(temp, A[j2][j2]);
        }
      }
      for (int i = 0; i < j; ++i)
        A[i][j] = __fmul_rn(ajj, A[i][j]);
    }
    // ---- sgetri sweep ----
    float work[4];
    for (int j = 3; j >= 0; --j) {
      for (int i = j + 1; i < 4; ++i) { work[i] = A[i][j]; A[i][j] = 0.0f; }
      for (int k = j + 1; k < 4; ++k) {
        float temp = -work[k];
        for (int i = 0; i < 4; ++i)
          A[i][j] = __fadd_rn(A[i][j], __fmul_rn(temp, A[i][k]));
      }
    }
    // ---- column interchanges ----
    for (int j = 2; j >= 0; --j) {
      int jp = ipiv[j];
      if (jp != j)
        for (int i = 0; i < 4; ++i) { float tmp = A[i][j]; A[i][j] = A[i][jp]; A[i][jp] = tmp; }
    }
    float* O = e2c + t * 12;
    for (int i = 0; i < 3; ++i)
      for (int j = 0; j < 4; ++j) O[i * 4 + j] = A[i][j];
  }
  // W transpose: wt[k*128 + o] = wd[o*256 + k]   (64 blocks x 512 = 32768)
  int idx = blockIdx.x * 512 + t;
  int k = idx >> 7, o = idx & 127;
  wt[idx] = (o < OTOT) ? wd[o * 256 + k] : 0.f;
}

// ---------------- kernel 1: GEMM x = F^T * W^T  (pure, no bias/softmax)
// grid 264 = 12 bn x 11 px-tiles(64) x 2 o-tiles(64). 256 thr / 4 waves,
// each wave owns a K-quarter; 8px x 8o register tile per lane.
__global__ __launch_bounds__(256) void k_gemm2(const float* __restrict__ img,
    const float* __restrict__ wt, float* __restrict__ xws) {
  __shared__ float smem[2 * KC * 68];   // 69,632 B: fbuf | wbuf (reused for reduce)
  float* fb = smem;
  float* wb = smem + KC * 68;
  const int tid = threadIdx.x;
  const int bid = blockIdx.x;
  const int ot  = bid & 1;
  const int pt  = (bid >> 1) % 11;
  const int bn  = bid / 22;
  const int px0 = pt * 64;
  const int o0  = ot * 64;
  const int lane = tid & 63;
  const int wv   = tid >> 6;
  const int pxg  = lane & 7;   // px-group: px = pxg*8 + i
  const int og   = lane >> 3;  // o-group:  o  = og*8  + j

  const float* fsrc = img + (size_t)bn * CINC * PIXN + px0;  // rows [k][704]
  const float* wsrc = wt + o0;                               // rows [k][128]

  float acc[8][8];
#pragma unroll
  for (int i = 0; i < 8; ++i)
#pragma unroll
    for (int j = 0; j < 8; ++j) acc[i][j] = 0.f;

  for (int chunk = 0; chunk < 2; ++chunk) {
    __syncthreads();
    // stage F chunk: 128k x 64px, aligned float4 copies, conflict-free
#pragma unroll
    for (int r = 0; r < 8; ++r) {
      int idx = r * 256 + tid;            // 0..2047
      int k = idx >> 4, pq = idx & 15;
      float4 v = *(const float4*)(fsrc + (size_t)(chunk * KC + k) * PIXN + pq * 4);
      *(float4*)(fb + k * 68 + pq * 4) = v;
    }
    // stage W chunk: 128k x 64o
#pragma unroll
    for (int r = 0; r < 8; ++r) {
      int idx = r * 256 + tid;
      int k = idx >> 4, oq = idx & 15;
      float4 v = *(const float4*)(wsrc + (size_t)(chunk * KC + k) * 128 + oq * 4);
      *(float4*)(wb + k * 68 + oq * 4) = v;
    }
    __syncthreads();
    // wave wv covers k in [wv*32, wv*32+32) of this chunk
    for (int ks = 0; ks < 8; ++ks) {
      int kk0 = wv * 32 + ks * 4;
      float fv[4][8], wvv[4][8];
#pragma unroll
      for (int kk = 0; kk < 4; ++kk) {
        const float* fr = fb + (kk0 + kk) * 68 + pxg * 8;
        const float* wr = wb + (kk0 + kk) * 68 + og * 8;
        float4 a = *(const float4*)(fr);
        float4 b = *(const float4*)(fr + 4);
        float4 c = *(const float4*)(wr);
        float4 d = *(const float4*)(wr + 4);
        fv[kk][0] = a.x; fv[kk][1] = a.y; fv[kk][2] = a.z; fv[kk][3] = a.w;
        fv[kk][4] = b.x; fv[kk][5] = b.y; fv[kk][6] = b.z; fv[kk][7] = b.w;
        wvv[kk][0] = c.x; wvv[kk][1] = c.y; wvv[kk][2] = c.z; wvv[kk][3] = c.w;
        wvv[kk][4] = d.x; wvv[kk][5] = d.y; wvv[kk][6] = d.z; wvv[kk][7] = d.w;
      }
#pragma unroll
      for (int kk = 0; kk < 4; ++kk)
#pragma unroll
        for (int i = 0; i < 8; ++i)
#pragma unroll
          for (int j = 0; j < 8; ++j)
            acc[i][j] += fv[kk][i] * wvv[kk][j];
    }
  }
  // ---- K-quarter reduce across the 4 waves (lane stride 68 -> uniform banks)
  __syncthreads();
  if (wv > 0) {
    float* dst = smem + (wv - 1) * 4352 + lane * 68;
#pragma unroll
    for (int i = 0; i < 8; ++i) {
      *(float4*)(dst + i * 8)     = make_float4(acc[i][0], acc[i][1], acc[i][2], acc[i][3]);
      *(float4*)(dst + i * 8 + 4) = make_float4(acc[i][4], acc[i][5], acc[i][6], acc[i][7]);
    }
  }
  __syncthreads();
  if (wv == 0) {
#pragma unroll
    for (int r = 0; r < 3; ++r) {
      const float* srcp = smem + r * 4352 + lane * 68;
#pragma unroll
      for (int i = 0; i < 8; ++i) {
        float4 v0 = *(const float4*)(srcp + i * 8);
        float4 v1 = *(const float4*)(srcp + i * 8 + 4);
        acc[i][0] += v0.x; acc[i][1] += v0.y; acc[i][2] += v0.z; acc[i][3] += v0.w;
        acc[i][4] += v1.x; acc[i][5] += v1.y; acc[i][6] += v1.z; acc[i][7] += v1.w;
      }
    }
    float* xrow = xws + ((size_t)bn * PIXN + px0) * 128 + o0 + og * 8;
#pragma unroll
    for (int i = 0; i < 8; ++i) {
      int px = pxg * 8 + i;
      *(float4*)(xrow + px * 128)     = make_float4(acc[i][0], acc[i][1], acc[i][2], acc[i][3]);
      *(float4*)(xrow + px * 128 + 4) = make_float4(acc[i][4], acc[i][5], acc[i][6], acc[i][7]);
    }
  }
}

// ---------------- kernel 1b: bias + softmax + depth/feat writeback
// (inner logic verbatim from the verified fused epilogue; source is xws)
__global__ __launch_bounds__(512) void k_soft(const float* __restrict__ xws,
    const float* __restrict__ bd, float* __restrict__ depth_out,
    float* __restrict__ feat_ws) {
  __shared__ float sb[64 * 129];
  __shared__ float pm[8 * 64];
  __shared__ float psum[8 * 64];
  __shared__ float m_l[64], rs_l[64];
  const int tid  = threadIdx.x;
  const int bn   = blockIdx.x / 11;
  const int tile = blockIdx.x % 11;
  const int px0  = tile * 64;
  const float* xrow = xws + ((size_t)bn * PIXN + px0) * 128;
  for (int idx = tid; idx < 64 * 128; idx += 512) {
    int p = idx >> 7, o = idx & 127;
    float v = xrow[idx];
    v += (o < OTOT) ? bd[o] : 0.f;
    sb[p * 129 + o] = v;
  }
  __syncthreads();
  const int px  = tid & 63;
  const int rep = tid >> 6;
  const int d0 = rep * 8;
  const int d1 = (d0 + 8 < DD) ? d0 + 8 : DD;
  float mm = -3.4e38f;
  for (int d = d0; d < d1; ++d) mm = fmaxf(mm, sb[px * 129 + d]);
  pm[rep * 64 + px] = mm;
  __syncthreads();
  float m = pm[px];
#pragma unroll
  for (int r2 = 1; r2 < 8; ++r2) m = fmaxf(m, pm[r2 * 64 + px]);
  float ss = 0.f;
  for (int d = d0; d < d1; ++d) ss += expf(sb[px * 129 + d] - m);
  psum[rep * 64 + px] = ss;
  __syncthreads();
  float s = psum[px];
#pragma unroll
  for (int r2 = 1; r2 < 8; ++r2) s += psum[r2 * 64 + px];
  if (rep == 0) { m_l[px] = m; rs_l[px] = 1.f / s; }
  __syncthreads();
  float* drow = depth_out + ((size_t)bn * PIXN + px0) * DD;
  for (int idx = tid; idx < 64 * DD; idx += 512) {
    int p2 = idx / DD;
    int d  = idx - p2 * DD;
    drow[idx] = expf(sb[p2 * 129 + d] - m_l[p2]) * rs_l[p2];
  }
  float* frow = feat_ws + ((size_t)bn * PIXN + px0) * CO;
  for (int idx = tid; idx < 64 * CO; idx += 512) {
    int p2 = idx >> 6, of = idx & 63;
    frow[idx] = sb[p2 * 129 + 59 + of];
  }
}

// ---------------- kernel 2: per-(b,x,y,n,z) projection -> weight + pixel index
// DO NOT TOUCH — numerics verified (R16 PASS).
__global__ __launch_bounds__(256) void k_proj(const float* __restrict__ e2c,
    const float* __restrict__ Kin, const float* __restrict__ depth_out,
    float* __restrict__ w_ws, unsigned short* __restrict__ pix_ws) {
  int t = blockIdx.x * 256 + threadIdx.x;
  const int TOT = BB * YY * XX * 48;
  if (t >= TOT) return;
  int cell = t / 48;
  int nz = t - cell * 48;
  int b = cell >> 14;
  int rem = cell & 16383;
  int y = rem >> 7;
  int x = rem & 127;
  int n = nz >> 3;
  int z = nz & 7;
  float w = 0.f;
  int pix = 0;
  if (z < ZZ) {
    int bn = b * NN + n;
    const float* M = e2c + bn * 12;
    float vx = __fadd_rn(__fmul_rn((float)x, 0.8f), -51.2f);
    float vy = __fadd_rn(__fmul_rn((float)y, 0.8f), -51.2f);
    float vz = __fadd_rn(__fmul_rn((float)z, 1.0f), -2.5f);
    float c0 = __fadd_rn(__fadd_rn(__fadd_rn(__fmul_rn(M[0], vx), __fmul_rn(M[1], vy)),
                                   __fmul_rn(M[2], vz)), M[3]);
    float c1 = __fadd_rn(__fadd_rn(__fadd_rn(__fmul_rn(M[4], vx), __fmul_rn(M[5], vy)),
                                   __fmul_rn(M[6], vz)), M[7]);
    float zc = __fadd_rn(__fadd_rn(__fadd_rn(__fmul_rn(M[8], vx), __fmul_rn(M[9], vy)),
                                   __fmul_rn(M[10], vz)), M[11]);
    bool val = (zc > 0.5f);
    float zs = fmaxf(zc, 0.1f);
    float u = __fdiv_rn(c0, zs);
    float v = __fdiv_rn(c1, zs);
    const float* Kp = Kin + bn * 9;
    float imx = __fadd_rn(__fmul_rn(Kp[0], u), Kp[2]);
    float imy = __fadd_rn(__fmul_rn(Kp[4], v), Kp[5]);
    float fcx = __fmul_rn(imx, 0.0625f);
    float fcy = __fmul_rn(imy, 0.0625f);
    val = val && (fcx >= 0.f) && (fcx < 44.f) && (fcy >= 0.f) && (fcy < 16.f);
    int dbin = (int)truncf(__fsub_rn(zc, 1.0f));
    val = val && (dbin >= 0) && (dbin < DD);
    int ui = (int)truncf(fminf(fmaxf(fcx, 0.f), 43.f));
    int vi = (int)truncf(fminf(fmaxf(fcy, 0.f), 15.f));
    int d = min(max(dbin, 0), DD - 1);
    pix = vi * WW + ui;
    if (val) w = depth_out[((size_t)bn * PIXN + pix) * DD + d];
  }
  w_ws[t] = w;
  pix_ws[t] = (unsigned short)pix;
}

// ---------------- kernel 3: gather-accumulate into BEV
// v4: entry x column parallel (no ballot walk). R3 post-mortem: one heavy
// 16-cell tile cost ~12 us under the wave-per-cell serial walk — unmodelable
// ~4000cy per 8-entry batch + 16-wave barrier imbalance. Now: 256-thr/4-wave
// blocks; a wave covers 4 cells at once with lane=(cell c=lane>>4, colquad
// q=lane&15); each lane owns float4 of output cols and iterates e=0..47
// ASCENDING: acc=fmaf(w[c][e], feat[e][q*4..], acc). Nonzero terms hit in the
// same ascending order as the verified walk; interleaved invalid terms are
// fmaf(0,finite,acc)==acc exactly (w>0 iff valid; pix always in-bounds) ->
// bev bit-identical. All 48 loads per cell are independent -> pipelined, one
// drain. w/pix staged to LDS coalesced (768 contiguous per block). Uniform
// __ballot skip for whole-wave-invalid e.
__global__ __launch_bounds__(256, 4) void k_scatter(const float* __restrict__ w_ws,
    const unsigned short* __restrict__ pix_ws, const float* __restrict__ feat_ws,
    float* __restrict__ bev) {
  __shared__ float sm_w[16 * 48];
  __shared__ int   sm_p[16 * 48];
  __shared__ float sm_o[16 * 67];
  const int tid = threadIdx.x;
  const int gb = blockIdx.x;
  const int b = gb >> 10;
  const int rem = gb & 1023;
  const int y = rem >> 3;
  const int x0 = (rem & 7) << 4;
  const int base768 = ((b * YY + y) * XX + x0) * 48;   // 16 cells contiguous
  for (int i = tid; i < 768; i += 256) {
    sm_w[i] = w_ws[base768 + i];
    sm_p[i] = (int)pix_ws[base768 + i];
  }
  __syncthreads();
  const int lane = tid & 63;
  const int wv = tid >> 6;
  const int c = lane >> 4;          // cell within wave (0..3)
  const int q = lane & 15;          // column quad (0..15)
  const int xi = wv * 4 + c;        // cell within block (0..15)
  const int wbase = xi * 48;
  const float* fbase = feat_ws + ((size_t)b * NN * PIXN << 6) + q * 4;
  float4 acc = make_float4(0.f, 0.f, 0.f, 0.f);
#pragma unroll
  for (int e = 0; e < 48; ++e) {
    float we = sm_w[wbase + e];
    if (__ballot(we != 0.f)) {
      int pe = sm_p[wbase + e];
      const float* fr = fbase + (((e >> 3) * PIXN + pe) << 6);
      float4 v = *(const float4*)fr;
      acc.x = fmaf(we, v.x, acc.x);
      acc.y = fmaf(we, v.y, acc.y);
      acc.z = fmaf(we, v.z, acc.z);
      acc.w = fmaf(we, v.w, acc.w);
    }
  }
  *(float4*)&sm_o[xi * 67 + q * 4] = acc;
  __syncthreads();
  // transposed bev write: 16-float contiguous x-runs per (b,o,y)
#pragma unroll
  for (int k = 0; k < 4; ++k) {
    int idx = k * 256 + tid;
    int o = idx >> 4, x2 = idx & 15;
    bev[(((size_t)b * CO + o) * YY + y) * XX + x0 + x2] = sm_o[x2 * 67 + o];
  }
}

extern "C" void kernel_launch(void* const* d_in, const int* in_sizes, int n_in,
                              void* d_out, int out_size, void* d_ws, size_t ws_size,
                              hipStream_t stream) {
  const float* img = (const float*)d_in[0];
  const float* c2e = (const float*)d_in[1];
  const float* Kin = (const float*)d_in[2];
  const float* wd  = (const float*)d_in[3];
  const float* bd  = (const float*)d_in[4];

  float* bev = (float*)d_out;
  float* depth_out = bev + (size_t)BB * CO * YY * XX;

  float* e2c = (float*)d_ws;
  float* feat_ws = (float*)((char*)d_ws + 2048);
  float* w_ws = feat_ws + (size_t)BB * NN * PIXN * CO;
  unsigned short* pix_ws = (unsigned short*)(w_ws + (size_t)BB * YY * XX * 48);
  // Aliases (disjoint lifetimes in stream order):
  //   xws (4.33 MB, k_gemm2->k_soft) sits on w_ws (6.29 MB, k_proj->k_scatter)
  //   wt  (128 KB,  k_inv->k_gemm2)  sits on pix_ws (3.1 MB, k_proj->k_scatter)
  float* xws = w_ws;
  float* wt  = (float*)pix_ws;

  hipLaunchKernelGGL(k_inv, dim3(64), dim3(512), 0, stream, c2e, e2c, wd, wt);
  hipLaunchKernelGGL(k_gemm2, dim3(BB * NN * 22), dim3(256), 0, stream, img, wt, xws);
  hipLaunchKernelGGL(k_soft, dim3(BB * NN * 11), dim3(512), 0, stream, xws, bd, depth_out, feat_ws);
  hipLaunchKernelGGL(k_proj, dim3((BB * YY * XX * 48) / 256), dim3(256), 0, stream,
                     e2c, Kin, depth_out, w_ws, pix_ws);
  hipLaunchKernelGGL(k_scatter, dim3(BB * YY * 8), dim3(256), 0, stream,
                     w_ws, pix_ws, feat_ws, bev);
}

// Round 9
// 118.170 us; speedup vs baseline: 1.2952x; 1.0171x over previous
//
#include <hip/hip_runtime.h>
#include <cstdint>
#include <cstddef>

#define BB 2
#define NN 6
#define CINC 256
#define HH 16
#define WW 44
#define DD 59
#define CO 64
#define PIXN 704       // H*W
#define OTOT 123       // D+COUT
#define XX 128
#define YY 128
#define ZZ 7
#define KC 128         // K-chunk staged in LDS

// ---------------- kernel 1: GEMM x = F^T * W^T  (pure, no bias/softmax)
// v3: k_inv dispatch eliminated. (a) the 4x4 inverse body (DO NOT TOUCH —
// numerics verified R16 PASS) runs verbatim in block 0, tid<12; e2c is
// consumed only by k_proj two dispatches later (stream-ordered). (b) W is
// staged into wbuf[k][o] DIRECTLY from wd[o][k] (the old wt precompute is
// deleted): per wave one k-row, o=0..63 consecutive -> LDS 2-way = free;
// global reads are uncoalesced but W = 126 KB L2-resident (~0.5us agg).
// Staged values are bit-identical to the old wt (zeros for o>=123), the
// GEMM loop is untouched -> xws bitwise unchanged vs the verified R8 build.
// grid 264 = 12 bn x 11 px-tiles(64) x 2 o-tiles(64). 256 thr / 4 waves,
// each wave owns a K-quarter; 8px x 8o register tile per lane.
__global__ __launch_bounds__(256) void k_gemm2(const float* __restrict__ img,
    const float* __restrict__ wd, const float* __restrict__ c2e,
    float* __restrict__ e2c, float* __restrict__ xws) {
  __shared__ float smem[2 * KC * 68];   // 69,632 B: fbuf | wbuf (reused for reduce)
  float* fb = smem;
  float* wb = smem + KC * 68;
  const int tid = threadIdx.x;
  const int bid = blockIdx.x;

  // ---- inline inv (verbatim k_inv body; block 0 only) ----
  if (bid == 0 && tid < BB * NN) {
    int t = tid;
    const float* M = c2e + t * 16;
    float A[4][4];
    int ipiv[4];
    for (int i = 0; i < 4; ++i)
      for (int j = 0; j < 4; ++j) A[i][j] = M[i * 4 + j];
    // ---- sgetf2 ----
    for (int j = 0; j < 4; ++j) {
      int p = j;
      float mx = fabsf(A[j][j]);
      for (int i = j + 1; i < 4; ++i) {
        float v = fabsf(A[i][j]);
        if (v > mx) { mx = v; p = i; }
      }
      ipiv[j] = p;
      if (p != j)
        for (int k = 0; k < 4; ++k) { float tmp = A[j][k]; A[j][k] = A[p][k]; A[p][k] = tmp; }
      if (j < 3) {
        float r = __fdiv_rn(1.0f, A[j][j]);
        for (int i = j + 1; i < 4; ++i) A[i][j] = __fmul_rn(A[i][j], r);
        for (int i = j + 1; i < 4; ++i)
          for (int k = j + 1; k < 4; ++k)
            A[i][k] = __fsub_rn(A[i][k], __fmul_rn(A[i][j], A[j][k]));
      }
    }
    // ---- strti2 ----
    for (int j = 0; j < 4; ++j) {
      A[j][j] = __fdiv_rn(1.0f, A[j][j]);
      float ajj = -A[j][j];
      for (int j2 = 0; j2 < j; ++j2) {
        float temp = A[j2][j];
        if (temp != 0.0f) {
          for (int i = 0; i < j2; ++i)
            A[i][j] = __fadd_rn(A[i][j], __fmul_rn(temp, A[i][j2]));
          A[j2][j] = __fmul_rn(temp, A[j2][j2]);
        }
      }
      for (int i = 0; i < j; ++i)
        A[i][j] = __fmul_rn(ajj, A[i][j]);
    }
    // ---- sgetri sweep ----
    float work[4];
    for (int j = 3; j >= 0; --j) {
      for (int i = j + 1; i < 4; ++i) { work[i] = A[i][j]; A[i][j] = 0.0f; }
      for (int k = j + 1; k < 4; ++k) {
        float temp = -work[k];
        for (int i = 0; i < 4; ++i)
          A[i][j] = __fadd_rn(A[i][j], __fmul_rn(temp, A[i][k]));
      }
    }
    // ---- column interchanges ----
    for (int j = 2; j >= 0; --j) {
      int jp = ipiv[j];
      if (jp != j)
        for (int i = 0; i < 4; ++i) { float tmp = A[i][j]; A[i][j] = A[i][jp]; A[i][jp] = tmp; }
    }
    float* O = e2c + t * 12;
    for (int i = 0; i < 3; ++i)
      for (int j = 0; j < 4; ++j) O[i * 4 + j] = A[i][j];
  }

  const int ot  = bid & 1;
  const int pt  = (bid >> 1) % 11;
  const int bn  = bid / 22;
  const int px0 = pt * 64;
  const int o0  = ot * 64;
  const int lane = tid & 63;
  const int wv   = tid >> 6;
  const int pxg  = lane & 7;   // px-group: px = pxg*8 + i
  const int og   = lane >> 3;  // o-group:  o  = og*8  + j

  const float* fsrc = img + (size_t)bn * CINC * PIXN + px0;  // rows [k][704]

  float acc[8][8];
#pragma unroll
  for (int i = 0; i < 8; ++i)
#pragma unroll
    for (int j = 0; j < 8; ++j) acc[i][j] = 0.f;

  for (int chunk = 0; chunk < 2; ++chunk) {
    __syncthreads();
    // stage F chunk: 128k x 64px, aligned float4 copies, conflict-free
#pragma unroll
    for (int r = 0; r < 8; ++r) {
      int idx = r * 256 + tid;            // 0..2047
      int k = idx >> 4, pq = idx & 15;
      float4 v = *(const float4*)(fsrc + (size_t)(chunk * KC + k) * PIXN + pq * 4);
      *(float4*)(fb + k * 68 + pq * 4) = v;
    }
    // stage W chunk: 128k x 64o, transposed from wd[o][k]. Per wave: one
    // k-quad row, o consecutive (LDS 2-way = free). o>=OTOT -> zeros,
    // matching the old wt padding exactly.
#pragma unroll
    for (int r = 0; r < 8; ++r) {
      int idx = r * 256 + tid;            // 0..2047
      int kq = idx >> 6;                  // 0..31 (k-quad within chunk)
      int o  = idx & 63;                  // 0..63
      float4 w4 = make_float4(0.f, 0.f, 0.f, 0.f);
      if (o0 + o < OTOT)
        w4 = *(const float4*)(wd + (size_t)(o0 + o) * CINC + chunk * KC + kq * 4);
      wb[(kq * 4 + 0) * 68 + o] = w4.x;
      wb[(kq * 4 + 1) * 68 + o] = w4.y;
      wb[(kq * 4 + 2) * 68 + o] = w4.z;
      wb[(kq * 4 + 3) * 68 + o] = w4.w;
    }
    __syncthreads();
    // wave wv covers k in [wv*32, wv*32+32) of this chunk
    for (int ks = 0; ks < 8; ++ks) {
      int kk0 = wv * 32 + ks * 4;
      float fv[4][8], wvv[4][8];
#pragma unroll
      for (int kk = 0; kk < 4; ++kk) {
        const float* fr = fb + (kk0 + kk) * 68 + pxg * 8;
        const float* wr = wb + (kk0 + kk) * 68 + og * 8;
        float4 a = *(const float4*)(fr);
        float4 b = *(const float4*)(fr + 4);
        float4 c = *(const float4*)(wr);
        float4 d = *(const float4*)(wr + 4);
        fv[kk][0] = a.x; fv[kk][1] = a.y; fv[kk][2] = a.z; fv[kk][3] = a.w;
        fv[kk][4] = b.x; fv[kk][5] = b.y; fv[kk][6] = b.z; fv[kk][7] = b.w;
        wvv[kk][0] = c.x; wvv[kk][1] = c.y; wvv[kk][2] = c.z; wvv[kk][3] = c.w;
        wvv[kk][4] = d.x; wvv[kk][5] = d.y; wvv[kk][6] = d.z; wvv[kk][7] = d.w;
      }
#pragma unroll
      for (int kk = 0; kk < 4; ++kk)
#pragma unroll
        for (int i = 0; i < 8; ++i)
#pragma unroll
          for (int j = 0; j < 8; ++j)
            acc[i][j] += fv[kk][i] * wvv[kk][j];
    }
  }
  // ---- K-quarter reduce across the 4 waves (lane stride 68 -> uniform banks)
  __syncthreads();
  if (wv > 0) {
    float* dst = smem + (wv - 1) * 4352 + lane * 68;
#pragma unroll
    for (int i = 0; i < 8; ++i) {
      *(float4*)(dst + i * 8)     = make_float4(acc[i][0], acc[i][1], acc[i][2], acc[i][3]);
      *(float4*)(dst + i * 8 + 4) = make_float4(acc[i][4], acc[i][5], acc[i][6], acc[i][7]);
    }
  }
  __syncthreads();
  if (wv == 0) {
#pragma unroll
    for (int r = 0; r < 3; ++r) {
      const float* srcp = smem + r * 4352 + lane * 68;
#pragma unroll
      for (int i = 0; i < 8; ++i) {
        float4 v0 = *(const float4*)(srcp + i * 8);
        float4 v1 = *(const float4*)(srcp + i * 8 + 4);
        acc[i][0] += v0.x; acc[i][1] += v0.y; acc[i][2] += v0.z; acc[i][3] += v0.w;
        acc[i][4] += v1.x; acc[i][5] += v1.y; acc[i][6] += v1.z; acc[i][7] += v1.w;
      }
    }
    float* xrow = xws + ((size_t)bn * PIXN + px0) * 128 + o0 + og * 8;
#pragma unroll
    for (int i = 0; i < 8; ++i) {
      int px = pxg * 8 + i;
      *(float4*)(xrow + px * 128)     = make_float4(acc[i][0], acc[i][1], acc[i][2], acc[i][3]);
      *(float4*)(xrow + px * 128 + 4) = make_float4(acc[i][4], acc[i][5], acc[i][6], acc[i][7]);
    }
  }
}

// ---------------- kernel 1b: bias + softmax + depth/feat writeback
// (inner logic verbatim from the verified fused epilogue; source is xws)
__global__ __launch_bounds__(512) void k_soft(const float* __restrict__ xws,
    const float* __restrict__ bd, float* __restrict__ depth_out,
    float* __restrict__ feat_ws) {
  __shared__ float sb[64 * 129];
  __shared__ float pm[8 * 64];
  __shared__ float psum[8 * 64];
  __shared__ float m_l[64], rs_l[64];
  const int tid  = threadIdx.x;
  const int bn   = blockIdx.x / 11;
  const int tile = blockIdx.x % 11;
  const int px0  = tile * 64;
  const float* xrow = xws + ((size_t)bn * PIXN + px0) * 128;
  for (int idx = tid; idx < 64 * 128; idx += 512) {
    int p = idx >> 7, o = idx & 127;
    float v = xrow[idx];
    v += (o < OTOT) ? bd[o] : 0.f;
    sb[p * 129 + o] = v;
  }
  __syncthreads();
  const int px  = tid & 63;
  const int rep = tid >> 6;
  const int d0 = rep * 8;
  const int d1 = (d0 + 8 < DD) ? d0 + 8 : DD;
  float mm = -3.4e38f;
  for (int d = d0; d < d1; ++d) mm = fmaxf(mm, sb[px * 129 + d]);
  pm[rep * 64 + px] = mm;
  __syncthreads();
  float m = pm[px];
#pragma unroll
  for (int r2 = 1; r2 < 8; ++r2) m = fmaxf(m, pm[r2 * 64 + px]);
  float ss = 0.f;
  for (int d = d0; d < d1; ++d) ss += expf(sb[px * 129 + d] - m);
  psum[rep * 64 + px] = ss;
  __syncthreads();
  float s = psum[px];
#pragma unroll
  for (int r2 = 1; r2 < 8; ++r2) s += psum[r2 * 64 + px];
  if (rep == 0) { m_l[px] = m; rs_l[px] = 1.f / s; }
  __syncthreads();
  float* drow = depth_out + ((size_t)bn * PIXN + px0) * DD;
  for (int idx = tid; idx < 64 * DD; idx += 512) {
    int p2 = idx / DD;
    int d  = idx - p2 * DD;
    drow[idx] = expf(sb[p2 * 129 + d] - m_l[p2]) * rs_l[p2];
  }
  float* frow = feat_ws + ((size_t)bn * PIXN + px0) * CO;
  for (int idx = tid; idx < 64 * CO; idx += 512) {
    int p2 = idx >> 6, of = idx & 63;
    frow[idx] = sb[p2 * 129 + 59 + of];
  }
}

// ---------------- kernel 2: per-(b,x,y,n,z) projection -> weight + pixel index
// DO NOT TOUCH — numerics verified (R16 PASS).
__global__ __launch_bounds__(256) void k_proj(const float* __restrict__ e2c,
    const float* __restrict__ Kin, const float* __restrict__ depth_out,
    float* __restrict__ w_ws, unsigned short* __restrict__ pix_ws) {
  int t = blockIdx.x * 256 + threadIdx.x;
  const int TOT = BB * YY * XX * 48;
  if (t >= TOT) return;
  int cell = t / 48;
  int nz = t - cell * 48;
  int b = cell >> 14;
  int rem = cell & 16383;
  int y = rem >> 7;
  int x = rem & 127;
  int n = nz >> 3;
  int z = nz & 7;
  float w = 0.f;
  int pix = 0;
  if (z < ZZ) {
    int bn = b * NN + n;
    const float* M = e2c + bn * 12;
    float vx = __fadd_rn(__fmul_rn((float)x, 0.8f), -51.2f);
    float vy = __fadd_rn(__fmul_rn((float)y, 0.8f), -51.2f);
    float vz = __fadd_rn(__fmul_rn((float)z, 1.0f), -2.5f);
    float c0 = __fadd_rn(__fadd_rn(__fadd_rn(__fmul_rn(M[0], vx), __fmul_rn(M[1], vy)),
                                   __fmul_rn(M[2], vz)), M[3]);
    float c1 = __fadd_rn(__fadd_rn(__fadd_rn(__fmul_rn(M[4], vx), __fmul_rn(M[5], vy)),
                                   __fmul_rn(M[6], vz)), M[7]);
    float zc = __fadd_rn(__fadd_rn(__fadd_rn(__fmul_rn(M[8], vx), __fmul_rn(M[9], vy)),
                                   __fmul_rn(M[10], vz)), M[11]);
    bool val = (zc > 0.5f);
    float zs = fmaxf(zc, 0.1f);
    float u = __fdiv_rn(c0, zs);
    float v = __fdiv_rn(c1, zs);
    const float* Kp = Kin + bn * 9;
    float imx = __fadd_rn(__fmul_rn(Kp[0], u), Kp[2]);
    float imy = __fadd_rn(__fmul_rn(Kp[4], v), Kp[5]);
    float fcx = __fmul_rn(imx, 0.0625f);
    float fcy = __fmul_rn(imy, 0.0625f);
    val = val && (fcx >= 0.f) && (fcx < 44.f) && (fcy >= 0.f) && (fcy < 16.f);
    int dbin = (int)truncf(__fsub_rn(zc, 1.0f));
    val = val && (dbin >= 0) && (dbin < DD);
    int ui = (int)truncf(fminf(fmaxf(fcx, 0.f), 43.f));
    int vi = (int)truncf(fminf(fmaxf(fcy, 0.f), 15.f));
    int d = min(max(dbin, 0), DD - 1);
    pix = vi * WW + ui;
    if (val) w = depth_out[((size_t)bn * PIXN + pix) * DD + d];
  }
  w_ws[t] = w;
  pix_ws[t] = (unsigned short)pix;
}

// ---------------- kernel 3: gather-accumulate into BEV
// v4 (verified R4/R8): entry x column parallel. 256-thr/4-wave blocks; wave
// covers 4 cells, lane=(cell c=lane>>4, colquad q=lane&15); each lane owns
// float4 of output cols, iterates e=0..47 ascending (bit-identical accum
// order; invalid terms are fmaf(0,finite,acc)==acc). w/pix staged via LDS.
__global__ __launch_bounds__(256, 4) void k_scatter(const float* __restrict__ w_ws,
    const unsigned short* __restrict__ pix_ws, const float* __restrict__ feat_ws,
    float* __restrict__ bev) {
  __shared__ float sm_w[16 * 48];
  __shared__ int   sm_p[16 * 48];
  __shared__ float sm_o[16 * 67];
  const int tid = threadIdx.x;
  const int gb = blockIdx.x;
  const int b = gb >> 10;
  const int rem = gb & 1023;
  const int y = rem >> 3;
  const int x0 = (rem & 7) << 4;
  const int base768 = ((b * YY + y) * XX + x0) * 48;   // 16 cells contiguous
  for (int i = tid; i < 768; i += 256) {
    sm_w[i] = w_ws[base768 + i];
    sm_p[i] = (int)pix_ws[base768 + i];
  }
  __syncthreads();
  const int lane = tid & 63;
  const int wv = tid >> 6;
  const int c = lane >> 4;          // cell within wave (0..3)
  const int q = lane & 15;          // column quad (0..15)
  const int xi = wv * 4 + c;        // cell within block (0..15)
  const int wbase = xi * 48;
  const float* fbase = feat_ws + ((size_t)b * NN * PIXN << 6) + q * 4;
  float4 acc = make_float4(0.f, 0.f, 0.f, 0.f);
#pragma unroll
  for (int e = 0; e < 48; ++e) {
    float we = sm_w[wbase + e];
    if (__ballot(we != 0.f)) {
      int pe = sm_p[wbase + e];
      const float* fr = fbase + (((e >> 3) * PIXN + pe) << 6);
      float4 v = *(const float4*)fr;
      acc.x = fmaf(we, v.x, acc.x);
      acc.y = fmaf(we, v.y, acc.y);
      acc.z = fmaf(we, v.z, acc.z);
      acc.w = fmaf(we, v.w, acc.w);
    }
  }
  *(float4*)&sm_o[xi * 67 + q * 4] = acc;
  __syncthreads();
  // transposed bev write: 16-float contiguous x-runs per (b,o,y)
#pragma unroll
  for (int k = 0; k < 4; ++k) {
    int idx = k * 256 + tid;
    int o = idx >> 4, x2 = idx & 15;
    bev[(((size_t)b * CO + o) * YY + y) * XX + x0 + x2] = sm_o[x2 * 67 + o];
  }
}

extern "C" void kernel_launch(void* const* d_in, const int* in_sizes, int n_in,
                              void* d_out, int out_size, void* d_ws, size_t ws_size,
                              hipStream_t stream) {
  const float* img = (const float*)d_in[0];
  const float* c2e = (const float*)d_in[1];
  const float* Kin = (const float*)d_in[2];
  const float* wd  = (const float*)d_in[3];
  const float* bd  = (const float*)d_in[4];

  float* bev = (float*)d_out;
  float* depth_out = bev + (size_t)BB * CO * YY * XX;

  float* e2c = (float*)d_ws;
  float* feat_ws = (float*)((char*)d_ws + 2048);
  float* w_ws = feat_ws + (size_t)BB * NN * PIXN * CO;
  unsigned short* pix_ws = (unsigned short*)(w_ws + (size_t)BB * YY * XX * 48);
  // Alias (disjoint lifetimes in stream order):
  //   xws (4.33 MB, k_gemm2->k_soft) sits on w_ws (6.29 MB, k_proj->k_scatter)
  float* xws = w_ws;

  hipLaunchKernelGGL(k_gemm2, dim3(BB * NN * 22), dim3(256), 0, stream,
                     img, wd, c2e, e2c, xws);
  hipLaunchKernelGGL(k_soft, dim3(BB * NN * 11), dim3(512), 0, stream, xws, bd, depth_out, feat_ws);
  hipLaunchKernelGGL(k_proj, dim3((BB * YY * XX * 48) / 256), dim3(256), 0, stream,
                     e2c, Kin, depth_out, w_ws, pix_ws);
  hipLaunchKernelGGL(k_scatter, dim3(BB * YY * 8), dim3(256), 0, stream,
                     w_ws, pix_ws, feat_ws, bev);
}